// Round 1
// baseline (115.672 us; speedup 1.0000x reference)
//
#include <hip/hip_runtime.h>
#include <math.h>

// Problem constants (match reference: T=2000, D=512, R=64)
#define RS 64
#define T_LEN 2000
#define D_LEN 512
#define L_CHUNK 64      // t-chunk length for the recurrence (P = trans^64)
#define N_CKPT 32       // ceil(T_LEN / L_CHUNK)
#define CT 16           // t-tile per block in the main kernel
#define N_TCHUNK (T_LEN / CT)  // 125

#define LOG_2PI_F 1.83787706640934534f
#define LOG2E_F   1.44269504088896340736f
#define LN2_F     0.69314718055994530942f

// ---------------------------------------------------------------------------
// Kernel A: one block. Compute P = transition^64 via 6 LDS squarings, then
// serially compute checkpoints h_{64c} = init_w @ P^c for c = 0..31.
// ---------------------------------------------------------------------------
__global__ __launch_bounds__(1024) void k_power(const float* __restrict__ trans,
                                                const float* __restrict__ initw,
                                                float* __restrict__ ckpt) {
    __shared__ float Abuf[RS][RS];
    __shared__ float Bbuf[RS][RS];
    __shared__ float hbuf[RS];
    const int tid = threadIdx.x;

    for (int idx = tid; idx < RS * RS; idx += 1024)
        Abuf[idx >> 6][idx & 63] = trans[idx];
    __syncthreads();

    // 6 squarings: Abuf holds T^(2^even), Bbuf T^(2^odd); result T^64 ends in Abuf.
    const int i  = tid >> 4;          // output row 0..63
    const int jb = (tid & 15) << 2;   // output col base (float4)
    for (int s = 0; s < 6; ++s) {
        float (*src)[RS] = (s & 1) ? Bbuf : Abuf;
        float (*dst)[RS] = (s & 1) ? Abuf : Bbuf;
        float a0 = 0.f, a1 = 0.f, a2 = 0.f, a3 = 0.f;
#pragma unroll 8
        for (int m = 0; m < RS; ++m) {
            const float rv = src[i][m];
            const float4 cv = *(const float4*)&src[m][jb];
            a0 = fmaf(rv, cv.x, a0);
            a1 = fmaf(rv, cv.y, a1);
            a2 = fmaf(rv, cv.z, a2);
            a3 = fmaf(rv, cv.w, a3);
        }
        // src/dst are distinct buffers -> no read/write hazard within this step.
        dst[i][jb + 0] = a0;
        dst[i][jb + 1] = a1;
        dst[i][jb + 2] = a2;
        dst[i][jb + 3] = a3;
        __syncthreads();  // dst becomes next step's src
    }

    // Checkpoint scan: h_{c+1} = h_c @ P  (P in Abuf). First wave only.
    if (tid < RS) hbuf[tid] = initw[tid];
    __syncthreads();
    for (int c = 0; c < N_CKPT; ++c) {
        if (tid < RS) ckpt[c * RS + tid] = hbuf[tid];
        float s0 = 0.f, s1 = 0.f, s2 = 0.f, s3 = 0.f;
        if (tid < RS) {
#pragma unroll 8
            for (int m = 0; m < RS; m += 4) {
                const float4 hv = *(const float4*)&hbuf[m];
                s0 = fmaf(hv.x, Abuf[m + 0][tid], s0);
                s1 = fmaf(hv.y, Abuf[m + 1][tid], s1);
                s2 = fmaf(hv.z, Abuf[m + 2][tid], s2);
                s3 = fmaf(hv.w, Abuf[m + 3][tid], s3);
            }
        }
        __syncthreads();
        if (tid < RS) hbuf[tid] = (s0 + s1) + (s2 + s3);
        __syncthreads();
    }
}

// ---------------------------------------------------------------------------
// Kernel B: 32 blocks x 64 threads. Block c runs the local serial recurrence
// from checkpoint c and emits b2[t][r] = (log h_norm - log sig - 0.5*log 2pi)
// * log2(e)   (log2 domain so the hot kernel uses native v_exp_f32).
// ---------------------------------------------------------------------------
__global__ __launch_bounds__(64) void k_logh(const float* __restrict__ trans,
                                             const float* __restrict__ sig,
                                             const float* __restrict__ ckpt,
                                             float* __restrict__ b2) {
    __shared__ float Tm[RS][RS];
    __shared__ float h[RS];
    const int j = threadIdx.x;
    const int c = blockIdx.x;

    for (int idx = j; idx < RS * RS; idx += RS)
        Tm[idx >> 6][idx & 63] = trans[idx];
    h[j] = ckpt[c * RS + j];
    const float cb = -logf(sig[j]) - 0.5f * LOG_2PI_F;
    __syncthreads();

    const int t0 = c * L_CHUNK;
    const int tend = min(t0 + L_CHUNK, T_LEN);
    for (int t = t0; t < tend; ++t) {
        float s0 = 0.f, s1 = 0.f, s2 = 0.f, s3 = 0.f;
        float w0 = 0.f, w1 = 0.f;
#pragma unroll 8
        for (int m = 0; m < RS; m += 4) {
            const float4 hv = *(const float4*)&h[m];
            s0 = fmaf(hv.x, Tm[m + 0][j], s0);
            s1 = fmaf(hv.y, Tm[m + 1][j], s1);
            s2 = fmaf(hv.z, Tm[m + 2][j], s2);
            s3 = fmaf(hv.w, Tm[m + 3][j], s3);
            w0 += hv.x + hv.y;
            w1 += hv.z + hv.w;
        }
        const float tot = w0 + w1;
        const float b = logf(h[j]) - logf(tot) + cb;
        b2[t * RS + j] = b * LOG2E_F;
        __syncthreads();
        h[j] = (s0 + s1) + (s2 + s3);
        __syncthreads();
    }
}

// ---------------------------------------------------------------------------
// Kernel C: the hot kernel. grid (D/256, T/CT); per thread: one d, CT t's.
// Per (t,d): 64-component logsumexp in log2 domain, 4-way reduction trees.
// Writes per-chunk partial sums (deterministic, no atomics).
// ---------------------------------------------------------------------------
__global__ __launch_bounds__(256) void k_main(const float* __restrict__ X,
                                              const float* __restrict__ sig,
                                              const float* __restrict__ mur,
                                              const float* __restrict__ b2,
                                              float* __restrict__ partial) {
    __shared__ float sb2[CT][RS];
    __shared__ float smu[RS];
    __shared__ float sc2[RS];
    const int tx = threadIdx.x;
    const int d  = blockIdx.x * 256 + tx;
    const int cy = blockIdx.y;

    // Cooperative tile load: CT*RS = 1024 floats = 256 threads * float4.
    {
        const float4 v = ((const float4*)(b2 + cy * CT * RS))[tx];
        ((float4*)&sb2[0][0])[tx] = v;
    }
    if (tx < RS) {
        const float s = sig[tx];
        smu[tx] = mur[tx];
        sc2[tx] = 0.5f * LOG2E_F / (s * s);
    }
    __syncthreads();

    float acc = 0.f;
    for (int tt = 0; tt < CT; ++tt) {
        const int t = cy * CT + tt;
        const float x = X[t * D_LEN + d];
        const float shift = 10.0f * (float)(t / 100 + 1);
        const float xr = x - shift;

        float a[RS];
        float m0 = -INFINITY, m1 = -INFINITY, m2 = -INFINITY, m3 = -INFINITY;
#pragma unroll
        for (int r = 0; r < RS; r += 4) {
            const float d0 = xr - smu[r + 0];
            const float d1 = xr - smu[r + 1];
            const float d2 = xr - smu[r + 2];
            const float d3 = xr - smu[r + 3];
            const float v0 = sb2[tt][r + 0] - sc2[r + 0] * d0 * d0;
            const float v1 = sb2[tt][r + 1] - sc2[r + 1] * d1 * d1;
            const float v2 = sb2[tt][r + 2] - sc2[r + 2] * d2 * d2;
            const float v3 = sb2[tt][r + 3] - sc2[r + 3] * d3 * d3;
            a[r + 0] = v0; a[r + 1] = v1; a[r + 2] = v2; a[r + 3] = v3;
            m0 = fmaxf(m0, v0); m1 = fmaxf(m1, v1);
            m2 = fmaxf(m2, v2); m3 = fmaxf(m3, v3);
        }
        const float mm = fmaxf(fmaxf(m0, m1), fmaxf(m2, m3));
        float s0 = 0.f, s1 = 0.f, s2 = 0.f, s3 = 0.f;
#pragma unroll
        for (int r = 0; r < RS; r += 4) {
            s0 += exp2f(a[r + 0] - mm);
            s1 += exp2f(a[r + 1] - mm);
            s2 += exp2f(a[r + 2] - mm);
            s3 += exp2f(a[r + 3] - mm);
        }
        acc += LN2_F * (mm + log2f((s0 + s1) + (s2 + s3)));
    }
    partial[cy * D_LEN + d] = acc;
}

// ---------------------------------------------------------------------------
// Kernel D: out[d] = sum over 125 chunks of partial[c][d].
// ---------------------------------------------------------------------------
__global__ __launch_bounds__(512) void k_reduce(const float* __restrict__ partial,
                                                float* __restrict__ out) {
    const int d = threadIdx.x;
    float s0 = 0.f, s1 = 0.f, s2 = 0.f, s3 = 0.f;
    int c = 0;
    for (; c + 4 <= N_TCHUNK; c += 4) {
        s0 += partial[(c + 0) * D_LEN + d];
        s1 += partial[(c + 1) * D_LEN + d];
        s2 += partial[(c + 2) * D_LEN + d];
        s3 += partial[(c + 3) * D_LEN + d];
    }
    for (; c < N_TCHUNK; ++c) s0 += partial[c * D_LEN + d];
    out[d] = (s0 + s1) + (s2 + s3);
}

// ---------------------------------------------------------------------------
extern "C" void kernel_launch(void* const* d_in, const int* in_sizes, int n_in,
                              void* d_out, int out_size, void* d_ws, size_t ws_size,
                              hipStream_t stream) {
    const float* X     = (const float*)d_in[0];  // [T, D]
    const float* trans = (const float*)d_in[1];  // [R, R]
    const float* sig   = (const float*)d_in[2];  // [R]
    const float* initw = (const float*)d_in[3];  // [R]
    const float* mur   = (const float*)d_in[4];  // [R]
    float* out = (float*)d_out;
    float* ws  = (float*)d_ws;

    // ws layout (floats): ckpt [32*64] @0, b2 [2000*64] @4096, partial [125*512] @135168
    // total = (4096 + 131072 + 64000) * 4B ~= 780 KB
    float* ckpt    = ws;
    float* b2      = ws + 4096;
    float* partial = ws + 4096 + 131072;

    k_power<<<1, 1024, 0, stream>>>(trans, initw, ckpt);
    k_logh<<<N_CKPT, RS, 0, stream>>>(trans, sig, ckpt, b2);
    dim3 gC(D_LEN / 256, N_TCHUNK);
    k_main<<<gC, 256, 0, stream>>>(X, sig, mur, b2, partial);
    k_reduce<<<1, 512, 0, stream>>>(partial, out);
}

// Round 2
// 83.000 us; speedup vs baseline: 1.3937x; 1.3937x over previous
//
#include <hip/hip_runtime.h>
#include <math.h>

// Problem constants (match reference: T=2000, D=512, R=64)
#define RS 64
#define T_LEN 2000
#define D_LEN 512
#define CT 8                    // t's per block in the fused main kernel
#define N_TCHUNK (T_LEN / CT)   // 250
#define NPOW 11                 // P_k = trans^(2^k), k = 0..10 (T_LEN < 2048)

#define LOG_2PI_F 1.83787706640934534f
#define LOG2E_F   1.44269504088896340736f
#define LN2_F     0.69314718055994530942f

// ---------------------------------------------------------------------------
// Kernel A: one block, 1024 threads. P[k] = trans^(2^k) for k=0..10 via 10
// LDS squarings (the only serial chain left; each squaring ~64-deep FMA loop
// with 4-output ILP per thread). Results stored to ws for the main kernel.
// ---------------------------------------------------------------------------
__global__ __launch_bounds__(1024) void k_power(const float* __restrict__ trans,
                                                float* __restrict__ P) {
    __shared__ float Abuf[RS][RS];
    __shared__ float Bbuf[RS][RS];
    const int tid = threadIdx.x;

    for (int idx = tid; idx < RS * RS; idx += 1024) {
        const float v = trans[idx];
        Abuf[idx >> 6][idx & 63] = v;
        P[idx] = v;                       // P_0 = trans
    }
    __syncthreads();

    const int i  = tid >> 4;              // output row 0..63
    const int jb = (tid & 15) << 2;       // output col base (float4)
    for (int s = 1; s < NPOW; ++s) {
        float (*src)[RS] = (s & 1) ? Abuf : Bbuf;   // s=1 reads T from Abuf
        float (*dst)[RS] = (s & 1) ? Bbuf : Abuf;
        float a0 = 0.f, a1 = 0.f, a2 = 0.f, a3 = 0.f;
#pragma unroll 8
        for (int m = 0; m < RS; ++m) {
            const float rv = src[i][m];
            const float4 cv = *(const float4*)&src[m][jb];
            a0 = fmaf(rv, cv.x, a0);
            a1 = fmaf(rv, cv.y, a1);
            a2 = fmaf(rv, cv.z, a2);
            a3 = fmaf(rv, cv.w, a3);
        }
        dst[i][jb + 0] = a0;
        dst[i][jb + 1] = a1;
        dst[i][jb + 2] = a2;
        dst[i][jb + 3] = a3;
        *(float4*)&P[(s << 12) + (i << 6) + jb] = make_float4(a0, a1, a2, a3);
        __syncthreads();
    }
}

// ---------------------------------------------------------------------------
// Kernel C (fused): grid (D/256, T/CT), 256 threads (4 waves).
// Preamble: wave w computes h_t for t = cy*8+w and t+4 via binary
// decomposition over P_k (11 uniform steps; the two t's differ only in bit 2,
// so their dot products share every P-column load). Then the per-t log-weights
// b2 go to LDS and all 256 threads run the 64-component logsumexp hot loop.
// Writes per-chunk partials (deterministic, no atomics).
// ---------------------------------------------------------------------------
__global__ __launch_bounds__(256) void k_main(const float* __restrict__ X,
                                              const float* __restrict__ sig,
                                              const float* __restrict__ mur,
                                              const float* __restrict__ initw,
                                              const float* __restrict__ P,
                                              float* __restrict__ partial) {
    __shared__ float shA[4][RS];
    __shared__ float shB[4][RS];
    __shared__ float sb2[CT][RS];
    __shared__ float smu[RS];
    __shared__ float sc2[RS];

    const int tx = threadIdx.x;
    const int w  = tx >> 6;               // wave 0..3
    const int j  = tx & 63;               // lane
    const int dblk = blockIdx.x;
    const int cy   = blockIdx.y;
    const int tA = cy * CT + w;           // wave's first t
    const int tB = tA + 4;                // wave's second t (differs in bit 2)

    float ha = initw[j];
    float hb = ha;

    // --- h-trajectory preamble: 11 uniform steps ---
    for (int k = 0; k < NPOW; ++k) {
        shA[w][j] = ha;
        shB[w][j] = hb;
        __syncthreads();
        const bool onA = (tA >> k) & 1;
        const bool onB = (tB >> k) & 1;
        float na = ha, nb = hb;
        if (onA | onB) {                  // wave-uniform; no barrier inside
            const float* __restrict__ Pk = P + (k << 12);
            float a0 = 0.f, a1 = 0.f, b0 = 0.f, b1 = 0.f;
#pragma unroll 8
            for (int m = 0; m < RS; m += 2) {
                const float p0 = Pk[(m + 0) * RS + j];   // coalesced column
                const float p1 = Pk[(m + 1) * RS + j];
                a0 = fmaf(shA[w][m + 0], p0, a0);
                a1 = fmaf(shA[w][m + 1], p1, a1);
                b0 = fmaf(shB[w][m + 0], p0, b0);
                b1 = fmaf(shB[w][m + 1], p1, b1);
            }
            if (onA) na = a0 + a1;
            if (onB) nb = b0 + b1;
        }
        __syncthreads();                  // reads done before next write
        ha = na;
        hb = nb;
    }

    // Row totals via butterfly shuffle (wave = 64 lanes).
    float ta = ha, tb = hb;
#pragma unroll
    for (int off = 32; off; off >>= 1) {
        ta += __shfl_xor(ta, off);
        tb += __shfl_xor(tb, off);
    }
    const float cb = -log2f(sig[j]) - 0.5f * LOG_2PI_F * LOG2E_F;
    sb2[w][j]     = log2f(ha) - log2f(ta) + cb;
    sb2[w + 4][j] = log2f(hb) - log2f(tb) + cb;
    if (tx < RS) {
        const float s = sig[tx];
        smu[tx] = mur[tx];
        sc2[tx] = 0.5f * LOG2E_F / (s * s);
    }
    __syncthreads();

    // --- hot loop: 64-component logsumexp per (t, d) in log2 domain ---
    const int d = dblk * 256 + tx;
    float acc = 0.f;
    for (int tt = 0; tt < CT; ++tt) {
        const int t = cy * CT + tt;
        const float x = X[t * D_LEN + d];
        const float shift = 10.0f * (float)(t / 100 + 1);
        const float xr = x - shift;

        float a[RS];
        float m0 = -INFINITY, m1 = -INFINITY, m2 = -INFINITY, m3 = -INFINITY;
#pragma unroll
        for (int r = 0; r < RS; r += 4) {
            const float d0 = xr - smu[r + 0];
            const float d1 = xr - smu[r + 1];
            const float d2 = xr - smu[r + 2];
            const float d3 = xr - smu[r + 3];
            const float v0 = fmaf(-sc2[r + 0] * d0, d0, sb2[tt][r + 0]);
            const float v1 = fmaf(-sc2[r + 1] * d1, d1, sb2[tt][r + 1]);
            const float v2 = fmaf(-sc2[r + 2] * d2, d2, sb2[tt][r + 2]);
            const float v3 = fmaf(-sc2[r + 3] * d3, d3, sb2[tt][r + 3]);
            a[r + 0] = v0; a[r + 1] = v1; a[r + 2] = v2; a[r + 3] = v3;
            m0 = fmaxf(m0, v0); m1 = fmaxf(m1, v1);
            m2 = fmaxf(m2, v2); m3 = fmaxf(m3, v3);
        }
        const float mm = fmaxf(fmaxf(m0, m1), fmaxf(m2, m3));
        float s0 = 0.f, s1 = 0.f, s2 = 0.f, s3 = 0.f;
#pragma unroll
        for (int r = 0; r < RS; r += 4) {
            s0 += exp2f(a[r + 0] - mm);
            s1 += exp2f(a[r + 1] - mm);
            s2 += exp2f(a[r + 2] - mm);
            s3 += exp2f(a[r + 3] - mm);
        }
        acc += LN2_F * (mm + log2f((s0 + s1) + (s2 + s3)));
    }
    partial[cy * D_LEN + d] = acc;
}

// ---------------------------------------------------------------------------
// Kernel D: out[d] = sum over 250 chunks of partial[c][d]. 8 blocks x 64.
// f64 accumulation: 250 adds into a ~1.4e7 magnitude sum, free insurance.
// ---------------------------------------------------------------------------
__global__ __launch_bounds__(64) void k_reduce(const float* __restrict__ partial,
                                               float* __restrict__ out) {
    const int d = blockIdx.x * 64 + threadIdx.x;
    double s0 = 0.0, s1 = 0.0;
    int c = 0;
    for (; c + 2 <= N_TCHUNK; c += 2) {
        s0 += (double)partial[(c + 0) * D_LEN + d];
        s1 += (double)partial[(c + 1) * D_LEN + d];
    }
    for (; c < N_TCHUNK; ++c) s0 += (double)partial[c * D_LEN + d];
    out[d] = (float)(s0 + s1);
}

// ---------------------------------------------------------------------------
extern "C" void kernel_launch(void* const* d_in, const int* in_sizes, int n_in,
                              void* d_out, int out_size, void* d_ws, size_t ws_size,
                              hipStream_t stream) {
    const float* X     = (const float*)d_in[0];  // [T, D]
    const float* trans = (const float*)d_in[1];  // [R, R]
    const float* sig   = (const float*)d_in[2];  // [R]
    const float* initw = (const float*)d_in[3];  // [R]
    const float* mur   = (const float*)d_in[4];  // [R]
    float* out = (float*)d_out;
    float* ws  = (float*)d_ws;

    // ws layout (floats): P [11*4096] @0, partial [250*512] @45056
    // total = (45056 + 128000) * 4B ~= 692 KB
    float* P       = ws;
    float* partial = ws + NPOW * RS * RS;

    k_power<<<1, 1024, 0, stream>>>(trans, P);
    dim3 gC(D_LEN / 256, N_TCHUNK);
    k_main<<<gC, 256, 0, stream>>>(X, sig, mur, initw, P, partial);
    k_reduce<<<D_LEN / 64, 64, 0, stream>>>(partial, out);
}